// Round 11
// baseline (370.592 us; speedup 1.0000x reference)
//
#include <hip/hip_runtime.h>
#include <hip/hip_cooperative_groups.h>

namespace cg = cooperative_groups;

#define NV 200000
#define NPAIR 100000
#define NK 24
#define NCH 64
#define NTHREADS 256

// ws float offsets
#define PART_OFF 0            // 24*64*3 = 4608
#define ROT_OFF  4680         // 216
#define TR_OFF   4896         // 72
#define PF_OFF   4968         // 216

// DPP butterfly add: x += lane_permuted(x). All-VALU, no DS pipe.
template <int CTRL>
__device__ __forceinline__ float dpp_add(float x) {
    int y = __builtin_amdgcn_update_dpp(0, __float_as_int(x), CTRL, 0xf, 0xf, true);
    return x + __int_as_float(y);
}

// Non-temporal loads for single-use streams (bypass L2 allocation).
typedef float vfloat4 __attribute__((ext_vector_type(4)));
typedef float vfloat2 __attribute__((ext_vector_type(2)));

__device__ __forceinline__ float4 nt_load4(const float4* p) {
    vfloat4 r = __builtin_nontemporal_load((const vfloat4*)p);
    return make_float4(r.x, r.y, r.z, r.w);
}
__device__ __forceinline__ float2 nt_load2(const float2* p) {
    vfloat2 r = __builtin_nontemporal_load((const vfloat2*)p);
    return make_float2(r.x, r.y);
}
__device__ __forceinline__ float nt_load1(const float* p) {
    return __builtin_nontemporal_load(p);
}

// ---------------- shared phase bodies ---------------------------------------
__device__ __forceinline__ void phaseA_body(int v, const float* vt, const float* sd,
                                            const float* betas, float* out) {
    float b[10];
#pragma unroll
    for (int i = 0; i < 10; i++) b[i] = betas[i];
    size_t v3 = 3 * (size_t)v;
    float a0 = nt_load1(vt + v3), a1 = nt_load1(vt + v3 + 1), a2 = nt_load1(vt + v3 + 2);
    const float2* s2 = (const float2*)(sd) + (size_t)v * 15;
#pragma unroll
    for (int j = 0; j < 15; j++) {
        float2 s = nt_load2(s2 + j);
        const int e0 = 2 * j, e1 = 2 * j + 1;
        float p0 = s.x * b[e0 % 10];
        float p1 = s.y * b[e1 % 10];
        if (e0 / 10 == 0) a0 += p0; else if (e0 / 10 == 1) a1 += p0; else a2 += p0;
        if (e1 / 10 == 0) a0 += p1; else if (e1 / 10 == 1) a1 += p1; else a2 += p1;
    }
    out[v3] = a0; out[v3 + 1] = a1; out[v3 + 2] = a2;
}

struct DState {
    float4 b0, b1, b2, b3, b4, b5;
    float rr0, rr1, rr2, rr3, rr4, rr5, rr6, rr7, rr8, tt0, tt1, tt2;
    int h, kk;
};

__device__ __forceinline__ void phaseD_init(DState& st, int l, const float* ws) {
    const float4* pf4 = (const float4*)(ws + PF_OFF);   // 54 float4
    st.b0 = pf4[(l < 54) ? l      : l - 54];
    st.b1 = pf4[(l < 44) ? l + 10 : l - 44];
    st.b2 = pf4[(l < 34) ? l + 20 : l - 34];
    st.b3 = pf4[(l < 24) ? l + 30 : l - 24];
    st.b4 = pf4[(l < 14) ? l + 40 : l - 14];
    st.b5 = pf4[(l <  4) ? l + 50 : 0];
    st.h  = l >> 5;
    st.kk = l & 31;
    st.rr0=0; st.rr1=0; st.rr2=0; st.rr3=0; st.rr4=0; st.rr5=0;
    st.rr6=0; st.rr7=0; st.rr8=0; st.tt0=0; st.tt1=0; st.tt2=0;
    if (st.kk < 24) {
        const float* r = ws + ROT_OFF + st.kk * 9;
        st.rr0=r[0]; st.rr1=r[1]; st.rr2=r[2]; st.rr3=r[3]; st.rr4=r[4];
        st.rr5=r[5]; st.rr6=r[6]; st.rr7=r[7]; st.rr8=r[8];
        const float* tr = ws + TR_OFF + st.kk * 3;
        st.tt0=tr[0]; st.tt1=tr[1]; st.tt2=tr[2];
    }
}

__device__ __forceinline__ void phaseD_pair(const DState& st, int l, int p,
                                            const float* pd, const float* wts,
                                            float* out) {
    const float4* base = (const float4*)(pd) + (size_t)p * 324;
    float4 A0 = nt_load4(base + l);
    float4 A1 = nt_load4(base + l + 64);
    float4 A2 = nt_load4(base + l + 128);
    float4 A3 = nt_load4(base + l + 192);
    float4 A4 = nt_load4(base + l + 256);
    float4 A5 = make_float4(0.f, 0.f, 0.f, 0.f);
    if (l < 4) A5 = nt_load4(base + l + 320);

    int vmy = 2 * p + st.h;
    const float* vsp = out + (size_t)vmy * 3;
    float vsx = vsp[0], vsy = vsp[1], vsz = vsp[2];
    float wk = (st.kk < 24) ? nt_load1(wts + (size_t)vmy * 24 + st.kk) : 0.f;

    float d0 = A0.x * st.b0.x + A0.y * st.b0.y + A0.z * st.b0.z + A0.w * st.b0.w;
    float d1 = A1.x * st.b1.x + A1.y * st.b1.y + A1.z * st.b1.z + A1.w * st.b1.w;
    float d2 = A2.x * st.b2.x + A2.y * st.b2.y + A2.z * st.b2.z + A2.w * st.b2.w;
    float d3 = A3.x * st.b3.x + A3.y * st.b3.y + A3.z * st.b3.z + A3.w * st.b3.w;
    float d4 = A4.x * st.b4.x + A4.y * st.b4.y + A4.z * st.b4.z + A4.w * st.b4.w;
    float d5 = A5.x * st.b5.x + A5.y * st.b5.y + A5.z * st.b5.z + A5.w * st.b5.w;

    float s0 = (l < 54) ? d0 : 0.f;
    float s1 = ((l < 54) ? 0.f : d0) + ((l < 44) ? d1 : 0.f);
    float s2 = ((l < 44) ? 0.f : d1) + ((l < 34) ? d2 : 0.f);
    float s3 = ((l < 34) ? 0.f : d2) + ((l < 24) ? d3 : 0.f);
    float s4 = ((l < 24) ? 0.f : d3) + ((l < 14) ? d4 : 0.f);
    float s5 = ((l < 14) ? 0.f : d4) + d5;

    s0 = dpp_add<0xB1>(s0); s1 = dpp_add<0xB1>(s1); s2 = dpp_add<0xB1>(s2);
    s3 = dpp_add<0xB1>(s3); s4 = dpp_add<0xB1>(s4); s5 = dpp_add<0xB1>(s5);
    s0 = dpp_add<0x4E>(s0); s1 = dpp_add<0x4E>(s1); s2 = dpp_add<0x4E>(s2);
    s3 = dpp_add<0x4E>(s3); s4 = dpp_add<0x4E>(s4); s5 = dpp_add<0x4E>(s5);
    s0 = dpp_add<0x141>(s0); s1 = dpp_add<0x141>(s1); s2 = dpp_add<0x141>(s2);
    s3 = dpp_add<0x141>(s3); s4 = dpp_add<0x141>(s4); s5 = dpp_add<0x141>(s5);
    s0 = dpp_add<0x140>(s0); s1 = dpp_add<0x140>(s1); s2 = dpp_add<0x140>(s2);
    s3 = dpp_add<0x140>(s3); s4 = dpp_add<0x140>(s4); s5 = dpp_add<0x140>(s5);
    s0 += __shfl_xor(s0, 16, 64); s1 += __shfl_xor(s1, 16, 64); s2 += __shfl_xor(s2, 16, 64);
    s3 += __shfl_xor(s3, 16, 64); s4 += __shfl_xor(s4, 16, 64); s5 += __shfl_xor(s5, 16, 64);
    s0 += __shfl_xor(s0, 32, 64); s1 += __shfl_xor(s1, 32, 64); s2 += __shfl_xor(s2, 32, 64);
    s3 += __shfl_xor(s3, 32, 64); s4 += __shfl_xor(s4, 32, 64); s5 += __shfl_xor(s5, 32, 64);

    float vpx = vsx + (st.h ? s3 : s0);
    float vpy = vsy + (st.h ? s4 : s1);
    float vpz = vsz + (st.h ? s5 : s2);

    float m0 = wk * (st.rr0 * vpx + st.rr1 * vpy + st.rr2 * vpz + st.tt0);
    float m1 = wk * (st.rr3 * vpx + st.rr4 * vpy + st.rr5 * vpz + st.tt1);
    float m2 = wk * (st.rr6 * vpx + st.rr7 * vpy + st.rr8 * vpz + st.tt2);

    m0 = dpp_add<0xB1>(m0); m1 = dpp_add<0xB1>(m1); m2 = dpp_add<0xB1>(m2);
    m0 = dpp_add<0x4E>(m0); m1 = dpp_add<0x4E>(m1); m2 = dpp_add<0x4E>(m2);
    m0 = dpp_add<0x141>(m0); m1 = dpp_add<0x141>(m1); m2 = dpp_add<0x141>(m2);
    m0 = dpp_add<0x140>(m0); m1 = dpp_add<0x140>(m1); m2 = dpp_add<0x140>(m2);
    m0 += __shfl_xor(m0, 16, 64); m1 += __shfl_xor(m1, 16, 64); m2 += __shfl_xor(m2, 16, 64);

    if (st.kk < 3) {
        out[(size_t)vmy * 3 + st.kk] = (st.kk == 0) ? m0 : (st.kk == 1) ? m1 : m2;
    }
}

__device__ __forceinline__ void rodrigues_and_chain(int t, const float* pose,
                                                    float* ws,
                                                    float Jl[72], float Rl[24][9],
                                                    float Ar[24][9], float At[24][3]) {
    if (t < 24) {
        float rx = pose[3 * t], ry = pose[3 * t + 1], rz = pose[3 * t + 2];
        float tx = rx + 1e-12f, ty = ry + 1e-12f, tz = rz + 1e-12f;
        float th = sqrtf(tx * tx + ty * ty + tz * tz);
        float inv = 1.0f / th;
        float kx = rx * inv, ky = ry * inv, kz = rz * inv;
        float s = sinf(th), c = cosf(th), oc = 1.0f - c;
        float R00 = 1.f + oc * (-(ky * ky + kz * kz));
        float R01 = -s * kz + oc * kx * ky;
        float R02 =  s * ky + oc * kx * kz;
        float R10 =  s * kz + oc * kx * ky;
        float R11 = 1.f + oc * (-(kx * kx + kz * kz));
        float R12 = -s * kx + oc * ky * kz;
        float R20 = -s * ky + oc * kx * kz;
        float R21 =  s * kx + oc * ky * kz;
        float R22 = 1.f + oc * (-(kx * kx + ky * ky));
        Rl[t][0] = R00; Rl[t][1] = R01; Rl[t][2] = R02;
        Rl[t][3] = R10; Rl[t][4] = R11; Rl[t][5] = R12;
        Rl[t][6] = R20; Rl[t][7] = R21; Rl[t][8] = R22;
        float* pf = ws + PF_OFF + t * 9;
        pf[0] = R00 - 1.f; pf[1] = R01;       pf[2] = R02;
        pf[3] = R10;       pf[4] = R11 - 1.f; pf[5] = R12;
        pf[6] = R20;       pf[7] = R21;       pf[8] = R22 - 1.f;
    }
    __syncthreads();

    const int par[24] = {0,0,0,0,1,2,3,4,5,6,7,8,9,9,9,12,13,14,16,17,18,19,20,21};
    const int lvl[24] = {0,1,1,1,2,2,2,3,3,3,4,4,4,4,4,5,5,5,6,6,7,7,8,8};
    float rel0 = 0.f, rel1 = 0.f, rel2 = 0.f;
    int p = 0, myl = -1;
    if (t < 24) {
        p = par[t]; myl = lvl[t];
        if (t == 0) { rel0 = Jl[0]; rel1 = Jl[1]; rel2 = Jl[2]; }
        else {
            rel0 = Jl[3 * t]     - Jl[3 * p];
            rel1 = Jl[3 * t + 1] - Jl[3 * p + 1];
            rel2 = Jl[3 * t + 2] - Jl[3 * p + 2];
        }
    }
    for (int L = 0; L < 9; L++) {
        if (myl == L) {
            if (t == 0) {
#pragma unroll
                for (int e = 0; e < 9; e++) Ar[0][e] = Rl[0][e];
                At[0][0] = rel0; At[0][1] = rel1; At[0][2] = rel2;
            } else {
#pragma unroll
                for (int i = 0; i < 3; i++) {
                    float ai0 = Ar[p][i * 3], ai1 = Ar[p][i * 3 + 1], ai2 = Ar[p][i * 3 + 2];
#pragma unroll
                    for (int jj = 0; jj < 3; jj++) {
                        Ar[t][i * 3 + jj] = ai0 * Rl[t][jj] + ai1 * Rl[t][3 + jj] + ai2 * Rl[t][6 + jj];
                    }
                    At[t][i] = ai0 * rel0 + ai1 * rel1 + ai2 * rel2 + At[p][i];
                }
            }
        }
        __syncthreads();
    }
    if (t < 24) {
#pragma unroll
        for (int i = 0; i < 3; i++) {
            float tr = At[t][i] - (Ar[t][i * 3]     * Jl[3 * t] +
                                   Ar[t][i * 3 + 1] * Jl[3 * t + 1] +
                                   Ar[t][i * 3 + 2] * Jl[3 * t + 2]);
            ws[TR_OFF + t * 3 + i] = tr;
        }
#pragma unroll
        for (int e = 0; e < 9; e++) ws[ROT_OFF + t * 9 + e] = Ar[t][e];
    }
}

// ================= cooperative mega-kernel (NO min-waves cap!) ===============
// R9's 428us regression was __launch_bounds__(256,4) forcing VGPR<=128 and
// spilling phase D's DState to scratch (VGPR_Count=40 in counters). Let the
// allocator float; grid is sized at launch from the occupancy API.
__global__ __launch_bounds__(NTHREADS) void mega(const float* __restrict__ betas,
                                                 const float* __restrict__ pose,
                                                 const float* __restrict__ vt,
                                                 const float* __restrict__ sd,
                                                 const float* __restrict__ pd,
                                                 const float* __restrict__ jr,
                                                 const float* __restrict__ wts,
                                                 float* __restrict__ out,
                                                 float* __restrict__ ws) {
    cg::grid_group grid = cg::this_grid();
    const int tid = threadIdx.x;
    const int bid = blockIdx.x;
    const int nb  = gridDim.x;
    const int l = tid & 63;
    const int wv = tid >> 6;

    __shared__ float red[4][3];
    __shared__ float Jl[72];
    __shared__ float Rl[24][9];
    __shared__ float Ar[24][9];
    __shared__ float At[24][3];

    // phase A
    for (int v = bid * NTHREADS + tid; v < NV; v += nb * NTHREADS)
        phaseA_body(v, vt, sd, betas, out);
    grid.sync();

    // phase B
    for (int unit = bid; unit < NK * NCH; unit += nb) {
        int k = unit >> 6;
        int chunk = unit & 63;
        const float* row = jr + (size_t)k * NV;
        float a0 = 0.f, a1 = 0.f, a2 = 0.f;
        for (int v = chunk * 256 + tid; v < NV; v += NCH * 256) {
            float w = nt_load1(row + v);
            size_t v3 = 3 * (size_t)v;
            a0 = fmaf(w, out[v3], a0);
            a1 = fmaf(w, out[v3 + 1], a1);
            a2 = fmaf(w, out[v3 + 2], a2);
        }
#pragma unroll
        for (int off = 32; off; off >>= 1) {
            a0 += __shfl_xor(a0, off, 64);
            a1 += __shfl_xor(a1, off, 64);
            a2 += __shfl_xor(a2, off, 64);
        }
        if (l == 0) { red[wv][0] = a0; red[wv][1] = a1; red[wv][2] = a2; }
        __syncthreads();
        if (tid < 3) {
            float s = red[0][tid] + red[1][tid] + red[2][tid] + red[3][tid];
            ws[PART_OFF + unit * 3 + tid] = s;
        }
        __syncthreads();
    }
    grid.sync();

    // phase C
    if (bid == 0) {
        for (int idx = tid; idx < 72; idx += NTHREADS) {
            int k = idx / 3, c = idx % 3;
            float s = 0.f;
#pragma unroll
            for (int ch = 0; ch < NCH; ch++) s += ws[PART_OFF + (k * NCH + ch) * 3 + c];
            Jl[idx] = s;
        }
        __syncthreads();
        rodrigues_and_chain(tid, pose, ws, Jl, Rl, Ar, At);
    }
    grid.sync();

    // phase D
    {
        DState st;
        phaseD_init(st, l, ws);
        int wid = (bid << 2) + wv;
        int stride = nb << 2;
        for (int p = wid; p < NPAIR; p += stride)
            phaseD_pair(st, l, p, pd, wts, out);
    }
}

// ================= fallback 4-kernel path (proven R10, 117.3us) =============
__global__ __launch_bounds__(256) void kA(const float* __restrict__ vt,
                                          const float* __restrict__ sd,
                                          const float* __restrict__ betas,
                                          float* __restrict__ vs_out) {
    int v = blockIdx.x * 256 + threadIdx.x;
    if (v >= NV) return;
    phaseA_body(v, vt, sd, betas, vs_out);
}

__global__ __launch_bounds__(256) void kB(const float* __restrict__ jr,
                                          const float* __restrict__ vs,
                                          float* __restrict__ ws) {
    int k = blockIdx.x >> 6;
    int chunk = blockIdx.x & 63;
    const float* row = jr + (size_t)k * NV;
    float a0 = 0.f, a1 = 0.f, a2 = 0.f;
    for (int v = chunk * 256 + threadIdx.x; v < NV; v += NCH * 256) {
        float w = nt_load1(row + v);
        size_t v3 = 3 * (size_t)v;
        a0 = fmaf(w, vs[v3], a0);
        a1 = fmaf(w, vs[v3 + 1], a1);
        a2 = fmaf(w, vs[v3 + 2], a2);
    }
#pragma unroll
    for (int off = 32; off; off >>= 1) {
        a0 += __shfl_xor(a0, off, 64);
        a1 += __shfl_xor(a1, off, 64);
        a2 += __shfl_xor(a2, off, 64);
    }
    __shared__ float red[4][3];
    int lane = threadIdx.x & 63, wv = threadIdx.x >> 6;
    if (lane == 0) { red[wv][0] = a0; red[wv][1] = a1; red[wv][2] = a2; }
    __syncthreads();
    if (threadIdx.x < 3) {
        float s = red[0][threadIdx.x] + red[1][threadIdx.x] +
                  red[2][threadIdx.x] + red[3][threadIdx.x];
        ws[PART_OFF + blockIdx.x * 3 + threadIdx.x] = s;
    }
}

__global__ __launch_bounds__(64) void kC(const float* __restrict__ pose,
                                         float* __restrict__ ws) {
    __shared__ float Jl[72];
    __shared__ float Rl[24][9];
    __shared__ float Ar[24][9];
    __shared__ float At[24][3];
    int t = threadIdx.x;
    for (int idx = t; idx < 72; idx += 64) {
        int k = idx / 3, c = idx % 3;
        float s = 0.f;
#pragma unroll
        for (int ch = 0; ch < NCH; ch++) s += ws[PART_OFF + (k * NCH + ch) * 3 + c];
        Jl[idx] = s;
    }
    __syncthreads();
    rodrigues_and_chain(t, pose, ws, Jl, Rl, Ar, At);
}

__global__ __launch_bounds__(256) void kD(const float* __restrict__ pd,
                                          const float* __restrict__ wts,
                                          const float* __restrict__ ws,
                                          float* __restrict__ out) {
    int t = threadIdx.x;
    int l = t & 63;
    DState st;
    phaseD_init(st, l, ws);
    int wid = (blockIdx.x << 2) + (t >> 6);
    int stride = gridDim.x << 2;
    for (int p = wid; p < NPAIR; p += stride)
        phaseD_pair(st, l, p, pd, wts, out);
}

extern "C" void kernel_launch(void* const* d_in, const int* in_sizes, int n_in,
                              void* d_out, int out_size, void* d_ws, size_t ws_size,
                              hipStream_t stream) {
    const float* betas = (const float*)d_in[0];
    const float* pose  = (const float*)d_in[1];
    const float* vt    = (const float*)d_in[2];
    const float* sd    = (const float*)d_in[3];
    const float* pd    = (const float*)d_in[4];
    const float* jr    = (const float*)d_in[5];
    const float* wts   = (const float*)d_in[6];
    float* out = (float*)d_out;
    float* ws  = (float*)d_ws;

    int perCU = 0;
    hipError_t e = hipOccupancyMaxActiveBlocksPerMultiprocessor(&perCU, mega, NTHREADS, 0);
    hipError_t le = hipErrorUnknown;
    if (e == hipSuccess && perCU > 0) {
        int grid = perCU * 256;           // exactly co-resident
        if (grid > 2048) grid = 2048;
        void* args[] = {(void*)&betas, (void*)&pose, (void*)&vt, (void*)&sd,
                        (void*)&pd, (void*)&jr, (void*)&wts, (void*)&out, (void*)&ws};
        le = hipLaunchCooperativeKernel((const void*)mega, dim3(grid),
                                        dim3(NTHREADS), args, 0, stream);
    }
    if (le != hipSuccess) {
        kA<<<(NV + 255) / 256, 256, 0, stream>>>(vt, sd, betas, out);
        kB<<<NK * NCH, 256, 0, stream>>>(jr, out, ws);
        kC<<<1, 64, 0, stream>>>(pose, ws);
        kD<<<6250, 256, 0, stream>>>(pd, wts, ws, out);
    }
}

// Round 12
// 117.094 us; speedup vs baseline: 3.1649x; 3.1649x over previous
//
#include <hip/hip_runtime.h>

#define NV 200000
#define NPAIR 100000
#define NK 24
#define NCH 64

// ws float offsets
#define PART_OFF 0            // 24*64*3 = 4608
#define ROT_OFF  4680         // 216
#define TR_OFF   4896         // 72
#define PF_OFF   4968         // 216

// DPP butterfly add: x += lane_permuted(x). All-VALU, no DS pipe.
template <int CTRL>
__device__ __forceinline__ float dpp_add(float x) {
    int y = __builtin_amdgcn_update_dpp(0, __float_as_int(x), CTRL, 0xf, 0xf, true);
    return x + __int_as_float(y);
}

// Non-temporal loads for single-use streams (bypass L2 allocation).
typedef float vfloat4 __attribute__((ext_vector_type(4)));
typedef float vfloat2 __attribute__((ext_vector_type(2)));

__device__ __forceinline__ float4 nt_load4(const float4* p) {
    vfloat4 r = __builtin_nontemporal_load((const vfloat4*)p);
    return make_float4(r.x, r.y, r.z, r.w);
}
__device__ __forceinline__ float2 nt_load2(const float2* p) {
    vfloat2 r = __builtin_nontemporal_load((const vfloat2*)p);
    return make_float2(r.x, r.y);
}
__device__ __forceinline__ float nt_load1(const float* p) {
    return __builtin_nontemporal_load(p);
}

// ---------------- kernel A: v_shaped = v_template + shapedirs . betas --------
__global__ __launch_bounds__(256) void kA(const float* __restrict__ vt,
                                          const float* __restrict__ sd,
                                          const float* __restrict__ betas,
                                          float* __restrict__ vs_out) {
    int v = blockIdx.x * 256 + threadIdx.x;
    if (v >= NV) return;
    float b[10];
#pragma unroll
    for (int i = 0; i < 10; i++) b[i] = betas[i];
    size_t v3 = 3 * (size_t)v;
    float acc0 = nt_load1(vt + v3), acc1 = nt_load1(vt + v3 + 1), acc2 = nt_load1(vt + v3 + 2);
    const float2* s2 = (const float2*)(sd) + (size_t)v * 15;
#pragma unroll
    for (int j = 0; j < 15; j++) {
        float2 s = nt_load2(s2 + j);
        const int e0 = 2 * j, e1 = 2 * j + 1;
        float p0 = s.x * b[e0 % 10];
        float p1 = s.y * b[e1 % 10];
        if (e0 / 10 == 0) acc0 += p0; else if (e0 / 10 == 1) acc1 += p0; else acc2 += p0;
        if (e1 / 10 == 0) acc0 += p1; else if (e1 / 10 == 1) acc1 += p1; else acc2 += p1;
    }
    vs_out[v3] = acc0; vs_out[v3 + 1] = acc1; vs_out[v3 + 2] = acc2;
}

// ---------------- kernel B: per-(k,chunk) partial sums of J_regressor @ vs ---
__global__ __launch_bounds__(256) void kB(const float* __restrict__ jr,
                                          const float* __restrict__ vs,
                                          float* __restrict__ ws) {
    int k = blockIdx.x >> 6;
    int chunk = blockIdx.x & 63;
    const float* row = jr + (size_t)k * NV;
    float a0 = 0.f, a1 = 0.f, a2 = 0.f;
    for (int v = chunk * 256 + threadIdx.x; v < NV; v += NCH * 256) {
        float w = nt_load1(row + v);          // jr: single-use stream
        size_t v3 = 3 * (size_t)v;
        a0 = fmaf(w, vs[v3], a0);             // vs: reused across 24 k -> cached
        a1 = fmaf(w, vs[v3 + 1], a1);
        a2 = fmaf(w, vs[v3 + 2], a2);
    }
#pragma unroll
    for (int off = 32; off; off >>= 1) {
        a0 += __shfl_xor(a0, off, 64);
        a1 += __shfl_xor(a1, off, 64);
        a2 += __shfl_xor(a2, off, 64);
    }
    __shared__ float red[4][3];
    int lane = threadIdx.x & 63, wv = threadIdx.x >> 6;
    if (lane == 0) { red[wv][0] = a0; red[wv][1] = a1; red[wv][2] = a2; }
    __syncthreads();
    if (threadIdx.x < 3) {
        float s = red[0][threadIdx.x] + red[1][threadIdx.x] +
                  red[2][threadIdx.x] + red[3][threadIdx.x];
        ws[PART_OFF + blockIdx.x * 3 + threadIdx.x] = s;
    }
}

// ---------------- kernel C: J reduce, Rodrigues, depth-parallel chain --------
__global__ __launch_bounds__(64) void kC(const float* __restrict__ pose,
                                         float* __restrict__ ws) {
    __shared__ float Jl[72];
    __shared__ float Rl[24][9];
    __shared__ float Ar[24][9];
    __shared__ float At[24][3];
    int t = threadIdx.x;

    for (int idx = t; idx < 72; idx += 64) {
        int k = idx / 3, c = idx % 3;
        float s = 0.f;
#pragma unroll
        for (int ch = 0; ch < NCH; ch++) s += ws[PART_OFF + (k * NCH + ch) * 3 + c];
        Jl[idx] = s;
    }

    if (t < 24) {
        float rx = pose[3 * t], ry = pose[3 * t + 1], rz = pose[3 * t + 2];
        float tx = rx + 1e-12f, ty = ry + 1e-12f, tz = rz + 1e-12f;
        float th = sqrtf(tx * tx + ty * ty + tz * tz);
        float inv = 1.0f / th;
        float kx = rx * inv, ky = ry * inv, kz = rz * inv;
        float s = sinf(th), c = cosf(th), oc = 1.0f - c;
        float R00 = 1.f + oc * (-(ky * ky + kz * kz));
        float R01 = -s * kz + oc * kx * ky;
        float R02 =  s * ky + oc * kx * kz;
        float R10 =  s * kz + oc * kx * ky;
        float R11 = 1.f + oc * (-(kx * kx + kz * kz));
        float R12 = -s * kx + oc * ky * kz;
        float R20 = -s * ky + oc * kx * kz;
        float R21 =  s * kx + oc * ky * kz;
        float R22 = 1.f + oc * (-(kx * kx + ky * ky));
        Rl[t][0] = R00; Rl[t][1] = R01; Rl[t][2] = R02;
        Rl[t][3] = R10; Rl[t][4] = R11; Rl[t][5] = R12;
        Rl[t][6] = R20; Rl[t][7] = R21; Rl[t][8] = R22;
        float* pf = ws + PF_OFF + t * 9;
        pf[0] = R00 - 1.f; pf[1] = R01;       pf[2] = R02;
        pf[3] = R10;       pf[4] = R11 - 1.f; pf[5] = R12;
        pf[6] = R20;       pf[7] = R21;       pf[8] = R22 - 1.f;
    }
    __syncthreads();

    const int par[24] = {0,0,0,0,1,2,3,4,5,6,7,8,9,9,9,12,13,14,16,17,18,19,20,21};
    const int lvl[24] = {0,1,1,1,2,2,2,3,3,3,4,4,4,4,4,5,5,5,6,6,7,7,8,8};
    float rel0 = 0.f, rel1 = 0.f, rel2 = 0.f;
    int p = 0, myl = -1;
    if (t < 24) {
        p = par[t]; myl = lvl[t];
        if (t == 0) { rel0 = Jl[0]; rel1 = Jl[1]; rel2 = Jl[2]; }
        else {
            rel0 = Jl[3 * t]     - Jl[3 * p];
            rel1 = Jl[3 * t + 1] - Jl[3 * p + 1];
            rel2 = Jl[3 * t + 2] - Jl[3 * p + 2];
        }
    }
    for (int L = 0; L < 9; L++) {
        if (myl == L) {
            if (t == 0) {
#pragma unroll
                for (int e = 0; e < 9; e++) Ar[0][e] = Rl[0][e];
                At[0][0] = rel0; At[0][1] = rel1; At[0][2] = rel2;
            } else {
#pragma unroll
                for (int i = 0; i < 3; i++) {
                    float ai0 = Ar[p][i * 3], ai1 = Ar[p][i * 3 + 1], ai2 = Ar[p][i * 3 + 2];
#pragma unroll
                    for (int jj = 0; jj < 3; jj++) {
                        Ar[t][i * 3 + jj] = ai0 * Rl[t][jj] + ai1 * Rl[t][3 + jj] + ai2 * Rl[t][6 + jj];
                    }
                    At[t][i] = ai0 * rel0 + ai1 * rel1 + ai2 * rel2 + At[p][i];
                }
            }
        }
        __syncthreads();
    }
    if (t < 24) {
#pragma unroll
        for (int i = 0; i < 3; i++) {
            float tr = At[t][i] - (Ar[t][i * 3]     * Jl[3 * t] +
                                   Ar[t][i * 3 + 1] * Jl[3 * t + 1] +
                                   Ar[t][i * 3 + 2] * Jl[3 * t + 2]);
            ws[TR_OFF + t * 3 + i] = tr;
        }
#pragma unroll
        for (int e = 0; e < 9; e++) ws[ROT_OFF + t * 9 + e] = Ar[t][e];
    }
}

// ------- kernel D: wave-per-VERTEX-PAIR posedirs dot + half-wave skinning ----
// grid = 6250 blocks * 4 waves = 25000 waves; exactly 4 pairs per wave.
__global__ __launch_bounds__(256) void kD(const float* __restrict__ pd,
                                          const float* __restrict__ wts,
                                          const float* __restrict__ ws,
                                          float* __restrict__ out) {
    int t = threadIdx.x;
    int l = t & 63;

    const float4* pf4 = (const float4*)(ws + PF_OFF);   // 54 float4
    float4 b0 = pf4[(l < 54) ? l      : l - 54];
    float4 b1 = pf4[(l < 44) ? l + 10 : l - 44];
    float4 b2 = pf4[(l < 34) ? l + 20 : l - 34];
    float4 b3 = pf4[(l < 24) ? l + 30 : l - 24];
    float4 b4 = pf4[(l < 14) ? l + 40 : l - 14];
    float4 b5 = pf4[(l <  4) ? l + 50 : 0];

    int h  = l >> 5;
    int kk = l & 31;
    float rr0=0,rr1=0,rr2=0,rr3=0,rr4=0,rr5=0,rr6=0,rr7=0,rr8=0;
    float tt0=0, tt1=0, tt2=0;
    if (kk < 24) {
        const float* r = ws + ROT_OFF + kk * 9;
        rr0=r[0]; rr1=r[1]; rr2=r[2]; rr3=r[3]; rr4=r[4];
        rr5=r[5]; rr6=r[6]; rr7=r[7]; rr8=r[8];
        const float* tr = ws + TR_OFF + kk * 3;
        tt0=tr[0]; tt1=tr[1]; tt2=tr[2];
    }

    int wid = (blockIdx.x << 2) + (t >> 6);
    int stride = gridDim.x << 2;
    for (int p = wid; p < NPAIR; p += stride) {
        const float4* base = (const float4*)(pd) + (size_t)p * 324;
        float4 A0 = nt_load4(base + l);
        float4 A1 = nt_load4(base + l + 64);
        float4 A2 = nt_load4(base + l + 128);
        float4 A3 = nt_load4(base + l + 192);
        float4 A4 = nt_load4(base + l + 256);
        float4 A5 = make_float4(0.f, 0.f, 0.f, 0.f);
        if (l < 4) A5 = nt_load4(base + l + 320);

        int vmy = 2 * p + h;
        const float* vsp = out + (size_t)vmy * 3;      // v_shaped (L2-resident)
        float vsx = vsp[0], vsy = vsp[1], vsz = vsp[2];
        float wk = (kk < 24) ? nt_load1(wts + (size_t)vmy * 24 + kk) : 0.f;

        float d0 = A0.x * b0.x + A0.y * b0.y + A0.z * b0.z + A0.w * b0.w;
        float d1 = A1.x * b1.x + A1.y * b1.y + A1.z * b1.z + A1.w * b1.w;
        float d2 = A2.x * b2.x + A2.y * b2.y + A2.z * b2.z + A2.w * b2.w;
        float d3 = A3.x * b3.x + A3.y * b3.y + A3.z * b3.z + A3.w * b3.w;
        float d4 = A4.x * b4.x + A4.y * b4.y + A4.z * b4.z + A4.w * b4.w;
        float d5 = A5.x * b5.x + A5.y * b5.y + A5.z * b5.z + A5.w * b5.w;

        float s0 = (l < 54) ? d0 : 0.f;
        float s1 = ((l < 54) ? 0.f : d0) + ((l < 44) ? d1 : 0.f);
        float s2 = ((l < 44) ? 0.f : d1) + ((l < 34) ? d2 : 0.f);
        float s3 = ((l < 34) ? 0.f : d2) + ((l < 24) ? d3 : 0.f);
        float s4 = ((l < 24) ? 0.f : d3) + ((l < 14) ? d4 : 0.f);
        float s5 = ((l < 14) ? 0.f : d4) + d5;

        s0 = dpp_add<0xB1>(s0); s1 = dpp_add<0xB1>(s1); s2 = dpp_add<0xB1>(s2);
        s3 = dpp_add<0xB1>(s3); s4 = dpp_add<0xB1>(s4); s5 = dpp_add<0xB1>(s5);
        s0 = dpp_add<0x4E>(s0); s1 = dpp_add<0x4E>(s1); s2 = dpp_add<0x4E>(s2);
        s3 = dpp_add<0x4E>(s3); s4 = dpp_add<0x4E>(s4); s5 = dpp_add<0x4E>(s5);
        s0 = dpp_add<0x141>(s0); s1 = dpp_add<0x141>(s1); s2 = dpp_add<0x141>(s2);
        s3 = dpp_add<0x141>(s3); s4 = dpp_add<0x141>(s4); s5 = dpp_add<0x141>(s5);
        s0 = dpp_add<0x140>(s0); s1 = dpp_add<0x140>(s1); s2 = dpp_add<0x140>(s2);
        s3 = dpp_add<0x140>(s3); s4 = dpp_add<0x140>(s4); s5 = dpp_add<0x140>(s5);
        s0 += __shfl_xor(s0, 16, 64); s1 += __shfl_xor(s1, 16, 64); s2 += __shfl_xor(s2, 16, 64);
        s3 += __shfl_xor(s3, 16, 64); s4 += __shfl_xor(s4, 16, 64); s5 += __shfl_xor(s5, 16, 64);
        s0 += __shfl_xor(s0, 32, 64); s1 += __shfl_xor(s1, 32, 64); s2 += __shfl_xor(s2, 32, 64);
        s3 += __shfl_xor(s3, 32, 64); s4 += __shfl_xor(s4, 32, 64); s5 += __shfl_xor(s5, 32, 64);

        float vpx = vsx + (h ? s3 : s0);
        float vpy = vsy + (h ? s4 : s1);
        float vpz = vsz + (h ? s5 : s2);

        float m0 = wk * (rr0 * vpx + rr1 * vpy + rr2 * vpz + tt0);
        float m1 = wk * (rr3 * vpx + rr4 * vpy + rr5 * vpz + tt1);
        float m2 = wk * (rr6 * vpx + rr7 * vpy + rr8 * vpz + tt2);

        m0 = dpp_add<0xB1>(m0); m1 = dpp_add<0xB1>(m1); m2 = dpp_add<0xB1>(m2);
        m0 = dpp_add<0x4E>(m0); m1 = dpp_add<0x4E>(m1); m2 = dpp_add<0x4E>(m2);
        m0 = dpp_add<0x141>(m0); m1 = dpp_add<0x141>(m1); m2 = dpp_add<0x141>(m2);
        m0 = dpp_add<0x140>(m0); m1 = dpp_add<0x140>(m1); m2 = dpp_add<0x140>(m2);
        m0 += __shfl_xor(m0, 16, 64); m1 += __shfl_xor(m1, 16, 64); m2 += __shfl_xor(m2, 16, 64);

        if (kk < 3) {
            out[(size_t)vmy * 3 + kk] = (kk == 0) ? m0 : (kk == 1) ? m1 : m2;
        }
    }
}

extern "C" void kernel_launch(void* const* d_in, const int* in_sizes, int n_in,
                              void* d_out, int out_size, void* d_ws, size_t ws_size,
                              hipStream_t stream) {
    const float* betas = (const float*)d_in[0];
    const float* pose  = (const float*)d_in[1];
    const float* vt    = (const float*)d_in[2];
    const float* sd    = (const float*)d_in[3];
    const float* pd    = (const float*)d_in[4];
    const float* jr    = (const float*)d_in[5];
    const float* wts   = (const float*)d_in[6];
    float* out = (float*)d_out;
    float* ws  = (float*)d_ws;

    kA<<<(NV + 255) / 256, 256, 0, stream>>>(vt, sd, betas, out);
    kB<<<NK * NCH, 256, 0, stream>>>(jr, out, ws);
    kC<<<1, 64, 0, stream>>>(pose, ws);
    kD<<<6250, 256, 0, stream>>>(pd, wts, ws, out);
}